// Round 11
// baseline (889.810 us; speedup 1.0000x reference)
//
#include <hip/hip_runtime.h>
#include <math.h>

#define C_CH 54
#define CP   64      // candidate row stride: [0..53]=cand, 54=candsq, 55=tcand, 56=libmean
#define NT   20
#define NM   6
#define NK   120     // NM * NT
#define BLK  256
#define PIX_PER_BLK BLK            // 1 pixel per thread
#define NF4  (NK * CP / 4)         // 1920 f4 elements in the table

typedef float f4 __attribute__((ext_vector_type(4)));

// ---------------- prep: candidate table (CP=64 rows) into workspace ----------------
__global__ __launch_bounds__(256) void hadar_prep(
    const float* __restrict__ s_sky, const float* __restrict__ s_ground,
    const float* __restrict__ library, const float* __restrict__ wg,
    float* __restrict__ cand)
{
    __shared__ float xamb[C_CH];
    __shared__ float tc[NT];
    __shared__ float lm[NM];
    const int tid = threadIdx.x;
    if (tid < NT) tc[tid] = 250.0f + (float)tid * (100.0f / 19.0f);
    if (tid < C_CH) xamb[tid] = 0.5f * s_sky[tid] + 0.5f * s_ground[tid];
    if (tid < NM) {
        float s = 0.0f;
        for (int c = 0; c < C_CH; ++c) s += library[tid * C_CH + c];
        lm[tid] = s / (float)C_CH;
    }
    __syncthreads();

    const float c1 = 1.191042e-8f, c2 = 1.4387752f;
    for (int idx = tid; idx < NK * CP; idx += 256) {
        const int k = idx >> 6, c = idx & 63;
        float v = 0.0f;
        if (c < C_CH) {
            const int m = k / NT, t = k - m * NT;
            const float nu = wg[c];
            const float B = c1 * nu * nu * nu / expm1f(c2 * nu / tc[t]);
            const float e = library[m * C_CH + c];
            v = e * B + (1.0f - e) * xamb[c];
        }
        cand[idx] = v;
    }
    __syncthreads();

    if (tid < NK) {
        float s = 0.0f;
        for (int c = 0; c < C_CH; ++c) { float v = cand[tid * CP + c]; s += v * v; }
        const int m = tid / NT, t = tid - m * NT;
        cand[tid * CP + 54] = s;        // candsq
        cand[tid * CP + 55] = tc[t];    // best_t value for this k
        cand[tid * CP + 56] = lm[m];    // texture value for this k
    }
}

// ---------------- main: 1 pixel/thread; LDS-broadcast table, half-row ping-pong ----
// Ten-round synthesis:
//  * SMEM streaming (rounds 0/1/5/10) has ~1000 cyc/iter exposed scalar-miss
//    stall that TLP never hid -> 308-322us floor.
//  * LDS broadcast (round 4) had the right compute model (same-address reads
//    are conflict-free broadcast, ~120cyc latency vs ~140cyc FMA work/iter,
//    6 B/cyc/CU of LDS BW vs 128 peak) and failed ONLY on registers:
//    112 buffer regs + 108 row regs >> the 128 the allocator grants.
//  * Allocator heuristic (rounds 2/4 vs 5/10): it targets 2x the declared
//    MIN occupancy. waves_per_eu(2,2) -> 128 VGPRs. (4,4)/launch_bounds(,4) -> 64.
// This kernel: PPT=1 (54 row floats) + 2x7-f4 half-row ping-pong (56 regs)
// = ~124 live <= 128.  VALU-bound model: 16384 waves x 120 x ~140cyc / 1024
// SIMDs / 2.4GHz ~= 112us.
//
// ROUND-9 LESSON (do not touch): loss must use the exact cand[] values and the
// exact accumulation pattern: a[c&3] += row[c]*ce, c ascending 0..53,
// l = (ssq - 2*d) + candsq. Ascending k + strict '<' == reference first-min.

#define LOADH(B, F4OFF) { \
    const f4* __restrict__ Lr = Lc + (F4OFF); \
    _Pragma("unroll") for (int j = 0; j < 7; ++j) B[j] = Lr[j]; }

// half-row FMAs: channels CB..CB+27 (CB=28 half stops at c=53; candsq at B[6][2])
#define FMAPH(B, CB) { \
    _Pragma("unroll") for (int j = 0; j < 7; ++j) { \
        _Pragma("unroll") for (int e = 0; e < 4; ++e) { \
            const int c = (CB) + 4 * j + e; \
            if (c < C_CH) a[c & 3] += row0[c] * B[j][e]; \
        } } }

__global__ __launch_bounds__(BLK)
__attribute__((amdgpu_waves_per_eu(2, 2)))
void hadar_main(
    const float* __restrict__ s_obs,
    const float* __restrict__ library,
    const float* __restrict__ cand,
    float* __restrict__ out, float* __restrict__ partials, int N)
{
    __shared__ f4 ldsc[NF4];            // 30720 B candidate table
    __shared__ int2 bkm[PIX_PER_BLK];   // 2048 B
    __shared__ float red[BLK];          // 1024 B

    const int tid = threadIdx.x;
    const long long base = (long long)blockIdx.x * PIX_PER_BLK;
    const long long n0 = base + tid;
    const bool v0 = (n0 < N);

    // pixel row in VGPRs (54 floats); float2 loads (row stride 216 B, 8B aligned)
    float row0[C_CH];
    if (v0) {
        const float2* rp = (const float2*)(s_obs + n0 * C_CH);
        #pragma unroll
        for (int i = 0; i < C_CH / 2; ++i) {
            float2 w = rp[i];
            row0[2 * i] = w.x; row0[2 * i + 1] = w.y;
        }
    } else {
        #pragma unroll
        for (int c = 0; c < C_CH; ++c) row0[c] = 0.0f;
    }

    // ---- stage candidate table global -> LDS (coalesced b128) ----
    {
        const f4* __restrict__ gc = (const f4*)cand;
        for (int j = tid; j < NF4; j += BLK) ldsc[j] = gc[j];
    }

    // ssq, same sequential order as all passing kernels
    float ssq0 = 0.0f;
    #pragma unroll
    for (int c = 0; c < C_CH; ++c) ssq0 += row0[c] * row0[c];

    float bl0 = 3.4e38f;
    int bk0 = NK;

    __syncthreads();   // table staged

    const f4* __restrict__ Lc = ldsc;

    // ---- k-loop: half-row ping-pong (P = lo half, Q = hi half) ----
    f4 P[7], Q[7];
    int f0 = 0;                 // f4 offset of row k (16 f4 per row)
    LOADH(P, 0);                // row 0, channels 0-27
    #pragma unroll 1
    for (int k = 0; k < NK; ++k) {
        LOADH(Q, f0 + 7);       // row k, channels 28-55 (incl. candsq)
        float a[4] = {0.f, 0.f, 0.f, 0.f};
        FMAPH(P, 0);            // c = 0..27 while Q is in flight
        const int fn = (k + 1 < NK) ? f0 + 16 : 0;
        LOADH(P, fn);           // prefetch row k+1 lo (row 0 reload on last iter)
        FMAPH(Q, 28);           // c = 28..53
        const float sq = Q[6][2];   // slot 54 = candsq
        const float d = (a[0] + a[1]) + (a[2] + a[3]);
        const float l = (ssq0 - 2.0f * d) + sq;
        if (l < bl0) { bl0 = l; bk0 = k; }   // strict '<', ascending k = first-min
        f0 = fn;
    }

    if (!v0 || bk0 >= NK) bk0 = 0;   // clamp for safe table indexing

    const size_t NN = (size_t)N;
    const size_t NC = (size_t)C_CH * NN;
    const float* __restrict__ Lf = (const float*)ldsc;

    // ---- small per-pixel outputs (coalesced; table values from LDS) ----
    if (v0) {
        out[n0] = Lf[bk0 * CP + 55];                 // best_t
        out[NN + NC + n0] = 0.5f;                    // best_v
        out[2 * NN + NC + n0] = 0.0f;                // beta
        out[3 * NN + NC + n0] = Lf[bk0 * CP + 56];   // texture
    }

    // ---- block-coalesced writer for best_e and s_recon ----
    bkm[tid] = make_int2(bk0 * CP, (bk0 / NT) * C_CH);

    float lsum = v0 ? bl0 : 0.0f;
    __syncthreads();

    {
        float* __restrict__ be = out + NN + (size_t)base * C_CH;
        float* __restrict__ sr = out + 4 * NN + NC + (size_t)base * C_CH;
        int p = tid / C_CH;
        int c = tid - p * C_CH;
        #pragma unroll 2
        for (int j = tid; j < PIX_PER_BLK * C_CH; j += BLK) {   // 54 iterations
            const int2 o = bkm[p];
            const float ev = library[o.y + c];   // L1-resident (1.3 KB)
            const float sv = Lf[o.x + c];        // LDS
            if (base + p < N) { be[j] = ev; sr[j] = sv; }
            p += 4; c += 40;                     // j += 256 == 4 rows + 40 channels
            if (c >= C_CH) { c -= C_CH; ++p; }
        }
    }

    // ---- deterministic block reduction of best_loss sum ----
    red[tid] = lsum;
    __syncthreads();
    #pragma unroll
    for (int s = BLK / 2; s > 0; s >>= 1) {
        if (tid < s) red[tid] += red[tid + s];
        __syncthreads();
    }
    if (tid == 0) partials[blockIdx.x] = red[0];
}

// ---------------- final reduce: objective = mean(best_loss) ----------------
__global__ __launch_bounds__(256) void hadar_reduce(
    const float* __restrict__ partials, int nb, float* __restrict__ obj_out, float invN)
{
    __shared__ float red[256];
    float s = 0.0f;
    for (int i = threadIdx.x; i < nb; i += 256) s += partials[i];
    red[threadIdx.x] = s;
    __syncthreads();
    #pragma unroll
    for (int st = 128; st > 0; st >>= 1) {
        if (threadIdx.x < st) red[threadIdx.x] += red[threadIdx.x + st];
        __syncthreads();
    }
    if (threadIdx.x == 0) *obj_out = red[0] * invN;
}

extern "C" void kernel_launch(void* const* d_in, const int* in_sizes, int n_in,
                              void* d_out, int out_size, void* d_ws, size_t ws_size,
                              hipStream_t stream)
{
    const float* s_obs    = (const float*)d_in[0];
    const float* s_sky    = (const float*)d_in[1];
    const float* s_ground = (const float*)d_in[2];
    const float* library  = (const float*)d_in[3];
    const float* wg       = (const float*)d_in[4];
    float* out = (float*)d_out;

    const int N  = in_sizes[0] / C_CH;
    const int nb = (N + PIX_PER_BLK - 1) / PIX_PER_BLK;

    float* ws       = (float*)d_ws;
    float* cand     = ws;              // NK*CP = 7680 floats
    float* partials = ws + 8192;       // nb floats

    hadar_prep<<<1, 256, 0, stream>>>(s_sky, s_ground, library, wg, cand);
    hadar_main<<<nb, BLK, 0, stream>>>(s_obs, library, cand, out, partials, N);

    const size_t NN = (size_t)N;
    float* obj_out = out + 4 * NN + 2 * (size_t)C_CH * NN;
    hadar_reduce<<<1, 256, 0, stream>>>(partials, nb, obj_out, 1.0f / (float)N);
}

// Round 16
// 732.783 us; speedup vs baseline: 1.2143x; 1.2143x over previous
//
#include <hip/hip_runtime.h>
#include <math.h>

#define C_CH 54
#define CP   64      // candidate row stride: [0..53]=cand, 54=candsq, 55=tcand, 56=libmean
#define NT   20
#define NM   6
#define NK   120     // NM * NT
#define BLK  256
#define PIX_PER_BLK BLK            // 1 pixel per thread

typedef float sf16 __attribute__((ext_vector_type(16)));
typedef float sf8  __attribute__((ext_vector_type(8)));

// ---------------- prep: candidate table (CP=64 rows) into workspace ----------------
__global__ __launch_bounds__(256) void hadar_prep(
    const float* __restrict__ s_sky, const float* __restrict__ s_ground,
    const float* __restrict__ library, const float* __restrict__ wg,
    float* __restrict__ cand)
{
    __shared__ float xamb[C_CH];
    __shared__ float tc[NT];
    __shared__ float lm[NM];
    const int tid = threadIdx.x;
    if (tid < NT) tc[tid] = 250.0f + (float)tid * (100.0f / 19.0f);
    if (tid < C_CH) xamb[tid] = 0.5f * s_sky[tid] + 0.5f * s_ground[tid];
    if (tid < NM) {
        float s = 0.0f;
        for (int c = 0; c < C_CH; ++c) s += library[tid * C_CH + c];
        lm[tid] = s / (float)C_CH;
    }
    __syncthreads();

    const float c1 = 1.191042e-8f, c2 = 1.4387752f;
    for (int idx = tid; idx < NK * CP; idx += 256) {
        const int k = idx >> 6, c = idx & 63;
        float v = 0.0f;
        if (c < C_CH) {
            const int m = k / NT, t = k - m * NT;
            const float nu = wg[c];
            const float B = c1 * nu * nu * nu / expm1f(c2 * nu / tc[t]);
            const float e = library[m * C_CH + c];
            v = e * B + (1.0f - e) * xamb[c];
        }
        cand[idx] = v;
    }
    __syncthreads();

    if (tid < NK) {
        float s = 0.0f;
        for (int c = 0; c < C_CH; ++c) { float v = cand[tid * CP + c]; s += v * v; }
        const int m = tid / NT, t = tid - m * NT;
        cand[tid * CP + 54] = s;        // candsq
        cand[tid * CP + 55] = tc[t];    // best_t value for this k
        cand[tid * CP + 56] = lm[m];    // texture value for this k
    }
}

// element c of the current candidate row held in SGPRs (c is compile-time after unroll)
#define CE(c) ((c) < 16 ? q0[(c)] : (c) < 32 ? q1[(c)-16] : (c) < 48 ? q2[(c)-32] : q3[(c)-48])

// ---------------- main: 1 pixel/thread, candidate rows via scalar loads, NO rotation ----
// Twelve-round synthesis:
//  * SMEM is the only wave-granular broadcast on this HW: one s_load serves the
//    whole wave and lands in SGPRs directly usable as FMA operands. LDS
//    "broadcast" (round 11) costs 14 per-wave ds_read_b128 per candidate ->
//    537us of LDS-pipe time (measured 453us, LDS-bound). VMEM buffers spill
//    (rounds 2/4). SMEM round 0 = 308us = best. This kernel is round 0 with
//    ONE change: the per-wave k-rotation is removed.
//  * Rotation theory: 15 rotated start points keep the whole 30KB table live
//    across the CU's waves -> the 16KB scalar cache can never converge ->
//    every s_load convoy misses to L2 + queues at the shared SQC (~220 cyc
//    exposed stall/iter measured in round 0). Without rotation all waves
//    stream the same ascending-k sequence in loose lockstep: the leading wave
//    misses, trailing waves hit K$. Working set ~ a few rows << 16KB.
//  * Ascending k + strict '<' == reference first-min (no tie-break needed).
// ROUND-9 LESSON (do not touch): loss must use exact cand[] values and exact
// accumulation: a[c&3] += row[c]*ce, c ascending, l=(ssq-2d)+sq. absmax margin
// is one tie-flip wide (6.0 vs 7.0).
__global__ __launch_bounds__(BLK) void hadar_main(
    const float* __restrict__ s_obs,
    const float* __restrict__ library,
    const float* __restrict__ cand,
    float* __restrict__ out, float* __restrict__ partials, int N)
{
    const int tid = threadIdx.x;
    const long long base = (long long)blockIdx.x * PIX_PER_BLK;
    const long long n0 = base + tid;
    const bool v0 = (n0 < N);

    // pixel row in VGPRs (54 floats)
    float row0[C_CH];
    if (v0) {
        const float2* rp = (const float2*)(s_obs + n0 * C_CH);
        #pragma unroll
        for (int i = 0; i < C_CH / 2; ++i) {
            float2 w = rp[i];
            row0[2 * i] = w.x; row0[2 * i + 1] = w.y;
        }
    } else {
        #pragma unroll
        for (int c = 0; c < C_CH; ++c) row0[c] = 0.0f;
    }

    // ssq, same sequential order as all passing kernels
    float ssq0 = 0.0f;
    #pragma unroll
    for (int c = 0; c < C_CH; ++c) ssq0 += row0[c] * row0[c];

    float bl0 = 3.4e38f;
    int bk0 = 0;

    const float* pk = cand;
    #pragma unroll 1
    for (int k = 0; k < NK; ++k) {
        sf16 q0, q1, q2;
        sf8  q3;
        asm volatile("s_load_dwordx16 %0, %1, 0x0"  : "=s"(q0) : "s"(pk));
        asm volatile("s_load_dwordx16 %0, %1, 0x40" : "=s"(q1) : "s"(pk));
        asm volatile("s_load_dwordx16 %0, %1, 0x80" : "=s"(q2) : "s"(pk));
        asm volatile("s_load_dwordx8  %0, %1, 0xc0" : "=s"(q3) : "s"(pk));
        // tie the wait to the loaded values so consumers can't be hoisted above it
        asm volatile("s_waitcnt lgkmcnt(0)" : "+s"(q0), "+s"(q1), "+s"(q2), "+s"(q3));

        float a[4] = {0.f, 0.f, 0.f, 0.f};
        #pragma unroll
        for (int c = 0; c < C_CH; ++c) {
            a[c & 3] += row0[c] * CE(c);
        }
        const float sq = q3[6];   // slot 54 = candsq
        const float d = (a[0] + a[1]) + (a[2] + a[3]);
        const float l = (ssq0 - 2.0f * d) + sq;
        if (l < bl0) { bl0 = l; bk0 = k; }   // strict '<', ascending k = first-min

        pk += CP;
    }

    const size_t NN = (size_t)N;
    const size_t NC = (size_t)C_CH * NN;

    // ---- small per-pixel outputs (coalesced) ----
    if (v0) {
        const float* cr = cand + (size_t)bk0 * CP;
        out[n0] = cr[55];                      // best_t
        out[NN + NC + n0] = 0.5f;              // best_v
        out[2 * NN + NC + n0] = 0.0f;          // beta
        out[3 * NN + NC + n0] = cr[56];        // texture
    }

    // ---- block-coalesced writer for best_e and s_recon ----
    __shared__ int2 bkm[PIX_PER_BLK];   // {cand row offset, library row offset}
    bkm[tid] = make_int2(bk0 * CP, (bk0 / NT) * C_CH);

    float lsum = v0 ? bl0 : 0.0f;
    __syncthreads();

    {
        float* __restrict__ be = out + NN + (size_t)base * C_CH;
        float* __restrict__ sr = out + 4 * NN + NC + (size_t)base * C_CH;
        int p = tid / C_CH;
        int c = tid - p * C_CH;
        #pragma unroll 2
        for (int j = tid; j < PIX_PER_BLK * C_CH; j += BLK) {   // 54 iterations
            const int2 o = bkm[p];
            const float ev = library[o.y + c];   // L1-resident (1.3 KB)
            const float sv = cand[o.x + c];      // L1/L2-resident (30 KB)
            if (base + p < N) { be[j] = ev; sr[j] = sv; }
            p += 4; c += 40;                     // j += 256 == 4 rows + 40 channels
            if (c >= C_CH) { c -= C_CH; ++p; }
        }
    }

    // ---- deterministic block reduction of best_loss sum ----
    __shared__ float red[BLK];
    red[tid] = lsum;
    __syncthreads();
    #pragma unroll
    for (int s = BLK / 2; s > 0; s >>= 1) {
        if (tid < s) red[tid] += red[tid + s];
        __syncthreads();
    }
    if (tid == 0) partials[blockIdx.x] = red[0];
}

// ---------------- final reduce: objective = mean(best_loss) ----------------
__global__ __launch_bounds__(256) void hadar_reduce(
    const float* __restrict__ partials, int nb, float* __restrict__ obj_out, float invN)
{
    __shared__ float red[256];
    float s = 0.0f;
    for (int i = threadIdx.x; i < nb; i += 256) s += partials[i];
    red[threadIdx.x] = s;
    __syncthreads();
    #pragma unroll
    for (int st = 128; st > 0; st >>= 1) {
        if (threadIdx.x < st) red[threadIdx.x] += red[threadIdx.x + st];
        __syncthreads();
    }
    if (threadIdx.x == 0) *obj_out = red[0] * invN;
}

extern "C" void kernel_launch(void* const* d_in, const int* in_sizes, int n_in,
                              void* d_out, int out_size, void* d_ws, size_t ws_size,
                              hipStream_t stream)
{
    const float* s_obs    = (const float*)d_in[0];
    const float* s_sky    = (const float*)d_in[1];
    const float* s_ground = (const float*)d_in[2];
    const float* library  = (const float*)d_in[3];
    const float* wg       = (const float*)d_in[4];
    float* out = (float*)d_out;

    const int N  = in_sizes[0] / C_CH;
    const int nb = (N + PIX_PER_BLK - 1) / PIX_PER_BLK;

    float* ws       = (float*)d_ws;
    float* cand     = ws;              // NK*CP = 7680 floats
    float* partials = ws + 8192;       // nb floats

    hadar_prep<<<1, 256, 0, stream>>>(s_sky, s_ground, library, wg, cand);
    hadar_main<<<nb, BLK, 0, stream>>>(s_obs, library, cand, out, partials, N);

    const size_t NN = (size_t)N;
    float* obj_out = out + 4 * NN + 2 * (size_t)C_CH * NN;
    hadar_reduce<<<1, 256, 0, stream>>>(partials, nb, obj_out, 1.0f / (float)N);
}